// Round 2
// baseline (524.363 us; speedup 1.0000x reference)
//
#include <hip/hip_runtime.h>
#include <hip/hip_bf16.h>

#define BB 64
#define TT 1024
#define DD 512
#define NS 24

#define POT_OFF   65536
#define LENS_OFF  1638400
#define TRANS_OFF 1638464

// ---------------------------------------------------------------------------
// Kernel 1: pot = x @ W + b (+ boundary adds). Register double-buffered
// global->LDS staging: load chunk k+1 into regs while computing chunk k.
// Grid: 512 x 128, one row per thread.
// ---------------------------------------------------------------------------
__global__ __launch_bounds__(128) void gemm_pot(
    const float* __restrict__ x, const float* __restrict__ W,
    const float* __restrict__ bias, const float* __restrict__ trans,
    const float* __restrict__ lb, const float* __restrict__ rb,
    float* __restrict__ out)
{
  __shared__ float xs[128 * 36];   // 128 rows x 32-K chunk, stride 36 (16B-aligned, conflict-clean)
  const int tid = threadIdx.x;
  const int row0 = blockIdx.x * 128;
  const int row = row0 + tid;
  const int t = row & (TT - 1);

  float acc[NS];
#pragma unroll
  for (int nn = 0; nn < NS; ++nn) acc[nn] = bias[nn];
  if (t == 0) {
#pragma unroll
    for (int nn = 0; nn < NS; ++nn) acc[nn] += lb[nn];
  }
  if (t == TT - 1) {
#pragma unroll
    for (int nn = 0; nn < NS; ++nn) acc[nn] += rb[nn];
  }

  const float* xr = x + (size_t)row0 * DD;

  // register double buffer: prefetch chunk 0
  float4 buf[8];
#pragma unroll
  for (int i = 0; i < 8; ++i) {
    int f = tid + i * 128, r = f >> 3, c = f & 7;
    buf[i] = *(const float4*)(xr + (size_t)r * DD + c * 4);
  }

  for (int k0 = 0; k0 < DD; k0 += 32) {
    // regs -> LDS (prev compute's LDS reads already fenced by loop-end sync)
#pragma unroll
    for (int i = 0; i < 8; ++i) {
      int f = tid + i * 128, r = f >> 3, c = f & 7;
      *(float4*)(&xs[r * 36 + c * 4]) = buf[i];
    }
    __syncthreads();
    // issue next chunk's loads; results not needed until next iteration
    if (k0 + 32 < DD) {
#pragma unroll
      for (int i = 0; i < 8; ++i) {
        int f = tid + i * 128, r = f >> 3, c = f & 7;
        buf[i] = *(const float4*)(xr + (size_t)r * DD + (k0 + 32) + c * 4);
      }
    }
    // compute chunk from LDS; W addresses wave-uniform -> s_load broadcast
#pragma unroll
    for (int kk = 0; kk < 32; kk += 4) {
      float4 xv = *(const float4*)(&xs[tid * 36 + kk]);
      float xj[4] = {xv.x, xv.y, xv.z, xv.w};
#pragma unroll
      for (int j = 0; j < 4; ++j) {
        const int k = k0 + kk + j;
        const float xvj = xj[j];
#pragma unroll
        for (int nn = 0; nn < NS; ++nn)
          acc[nn] = fmaf(xvj, W[k * NS + nn], acc[nn]);
      }
    }
    __syncthreads();
  }

  float* po = out + POT_OFF + (size_t)row * NS;
#pragma unroll
  for (int i = 0; i < 6; ++i)
    *(float4*)(po + i * 4) = make_float4(acc[4*i], acc[4*i+1], acc[4*i+2], acc[4*i+3]);

  if (blockIdx.x == 0 && tid < BB) out[LENS_OFF + tid] = (float)TT;
  if (blockIdx.x == 1) {
    for (int i = tid; i < NS * NS; i += 128) out[TRANS_OFF + i] = trans[i];
  }
}

// ---------------------------------------------------------------------------
// Kernel 2: Viterbi forward scan. One block per batch; 16 waves stage the
// whole pot[b] (96 KB) into LDS, then wave 0 lanes 0..23 run the scan with
// alpha broadcast through SGPRs (v_readlane) and 8-deep LDS prefetch.
// ---------------------------------------------------------------------------
__global__ __launch_bounds__(1024) void viterbi_scan(
    const float* __restrict__ pot, const float* __restrict__ trans,
    float* __restrict__ alphas)
{
  __shared__ float ps[TT * NS + 8 * NS];   // +pad so tail prefetch stays in-bounds
  const int b = blockIdx.x;
  const int tid = threadIdx.x;

  {
    const float4* src = (const float4*)(pot + (size_t)b * TT * NS);
    float4* dst = (float4*)ps;
#pragma unroll
    for (int i = 0; i < 6; ++i) dst[tid + i * 1024] = src[tid + i * 1024];
  }
  __syncthreads();
  if (tid >= 24) return;          // lanes 24..63 masked off; readlane still reads 0..23
  const int n = tid;

  float tc[NS];
#pragma unroll
  for (int m = 0; m < NS; ++m) tc[m] = trans[m * NS + n];

  float* ab = alphas + (size_t)b * TT * NS;

  float a0 = ps[n];
  ab[n] = a0;
  float as[NS];
#pragma unroll
  for (int m = 0; m < NS; ++m)
    as[m] = __int_as_float(__builtin_amdgcn_readlane(__float_as_int(a0), m));

  float pv[8];
#pragma unroll
  for (int u = 0; u < 8; ++u) pv[u] = ps[(1 + u) * NS + n];

  auto step = [&](int tt, float potv) {
    float sc[NS];
#pragma unroll
    for (int m = 0; m < NS; ++m) sc[m] = as[m] + tc[m];
    float r0 = fmaxf(fmaxf(sc[0],  sc[1]),  sc[2]);
    float r1 = fmaxf(fmaxf(sc[3],  sc[4]),  sc[5]);
    float r2 = fmaxf(fmaxf(sc[6],  sc[7]),  sc[8]);
    float r3 = fmaxf(fmaxf(sc[9],  sc[10]), sc[11]);
    float r4 = fmaxf(fmaxf(sc[12], sc[13]), sc[14]);
    float r5 = fmaxf(fmaxf(sc[15], sc[16]), sc[17]);
    float r6 = fmaxf(fmaxf(sc[18], sc[19]), sc[20]);
    float r7 = fmaxf(fmaxf(sc[21], sc[22]), sc[23]);
    float q0 = fmaxf(fmaxf(r0, r1), r2);
    float q1 = fmaxf(fmaxf(r3, r4), r5);
    float q2 = fmaxf(r6, r7);
    float best = fmaxf(fmaxf(q0, q1), q2);
    float anew = best + potv;
    ab[(size_t)tt * NS + n] = anew;
#pragma unroll
    for (int m = 0; m < NS; ++m)
      as[m] = __int_as_float(__builtin_amdgcn_readlane(__float_as_int(anew), m));
  };

  for (int t = 1; t + 7 <= TT - 1; t += 8) {
#pragma unroll
    for (int u = 0; u < 8; ++u) {
      const int tt = t + u;
      const float potv = pv[u];
      pv[u] = ps[(tt + 8) * NS + n];   // lands in pad for tail — never consumed
      step(tt, potv);
    }
  }
  // steps 1017..1023
#pragma unroll
  for (int u = 0; u < 7; ++u) step(1017 + u, pv[u]);
}

// ---------------------------------------------------------------------------
// Kernel 3: reconstruct backpointers in parallel (bit-exact vs forward):
// bp[b][t][n] = first argmax_m( alpha[b][t-1][m] + trans[m][n] ), t in [1,T)
// ---------------------------------------------------------------------------
__global__ __launch_bounds__(256) void bp_build(
    const float* __restrict__ alphas, const float* __restrict__ trans,
    unsigned char* __restrict__ bp)
{
  const long total = (long)BB * (TT - 1) * NS;
  long idx = (long)blockIdx.x * 256 + threadIdx.x;
  if (idx >= total) return;
  const int nn = (int)(idx % NS);
  const long r = idx / NS;
  const int tm1 = (int)(r % (TT - 1));
  const int b = (int)(r / (TT - 1));
  const int t = tm1 + 1;

  const float* ar = alphas + ((size_t)b * TT + (t - 1)) * NS;
  float best = ar[0] + trans[0 * NS + nn];
  int bi = 0;
#pragma unroll
  for (int m = 1; m < NS; ++m) {
    float s = ar[m] + trans[m * NS + nn];
    bool g = s > best;                // strict > : first-max (jnp.argmax) semantics
    bi = g ? m : bi;
    best = g ? s : best;
  }
  bp[((size_t)b * TT + t) * NS + nn] = (unsigned char)bi;
}

// ---------------------------------------------------------------------------
// Kernel 4: backtrace via chunked function composition (C=32, 32 chunks).
// ---------------------------------------------------------------------------
__global__ __launch_bounds__(768) void backtrace(
    const unsigned char* __restrict__ bp, const float* __restrict__ alphas,
    float* __restrict__ out_dec)
{
  __shared__ unsigned char bl[TT * NS];   // 24576 B
  __shared__ int H[32][NS];
  __shared__ int e[32];

  const int b = blockIdx.x, tid = threadIdx.x;

  const uint4* src = (const uint4*)(bp + (size_t)b * TT * NS);
  uint4* dst = (uint4*)bl;
  for (int i = tid; i < (TT * NS) / 16; i += 768) dst[i] = src[i];
  __syncthreads();

  // C1: per-chunk composition tables
  {
    const int c = tid / NS, s = tid % NS;    // c in [0,32)
    int a = s;
    int tlo = c * 32; if (tlo < 1) tlo = 1;
    for (int t = c * 32 + 31; t >= tlo; --t) a = bl[t * NS + a];
    H[c][s] = a;
  }
  __syncthreads();

  // C2: last_tag + chunk-boundary tags (serial, 1 thread)
  if (tid == 0) {
    const float* ar = alphas + ((size_t)b * TT + (TT - 1)) * NS;
    float best = ar[0]; int bi = 0;
#pragma unroll
    for (int nn = 1; nn < NS; ++nn) {
      float v = ar[nn];
      if (v > best) { best = v; bi = nn; }
    }
    int tag = bi;
    e[31] = tag;
    for (int c = 31; c >= 1; --c) { tag = H[c][tag]; e[c - 1] = tag; }
  }
  __syncthreads();

  // C3: emit tags per chunk
  if (tid < 32) {
    const int c = tid;
    int tag = e[c];
    float* od = out_dec + (size_t)b * TT;
    od[c * 32 + 31] = (float)tag;
    for (int t = c * 32 + 30; t >= c * 32; --t) {
      tag = bl[(t + 1) * NS + tag];
      od[t] = (float)tag;
    }
  }
}

// ---------------------------------------------------------------------------
extern "C" void kernel_launch(void* const* d_in, const int* in_sizes, int n_in,
                              void* d_out, int out_size, void* d_ws, size_t ws_size,
                              hipStream_t stream)
{
  const float* x     = (const float*)d_in[0];
  const float* W     = (const float*)d_in[1];
  const float* bias  = (const float*)d_in[2];
  const float* trans = (const float*)d_in[3];
  const float* lb    = (const float*)d_in[4];
  const float* rb    = (const float*)d_in[5];
  float* out = (float*)d_out;

  float* alphas = (float*)d_ws;                                        // 6 MB
  unsigned char* bp = (unsigned char*)d_ws + (size_t)BB * TT * NS * 4; // 1.5 MB

  gemm_pot<<<512, 128, 0, stream>>>(x, W, bias, trans, lb, rb, out);
  viterbi_scan<<<BB, 1024, 0, stream>>>(out + POT_OFF, trans, alphas);
  const long total = (long)BB * (TT - 1) * NS;
  bp_build<<<(int)((total + 255) / 256), 256, 0, stream>>>(alphas, trans, bp);
  backtrace<<<BB, 768, 0, stream>>>(bp, alphas, out);
}

// Round 3
// 472.677 us; speedup vs baseline: 1.1093x; 1.1093x over previous
//
#include <hip/hip_runtime.h>
#include <hip/hip_bf16.h>

#define BB 64
#define TT 1024
#define DD 512
#define NS 24

#define POT_OFF   65536
#define LENS_OFF  1638400
#define TRANS_OFF 1638464

// ---------------------------------------------------------------------------
// Kernel 1: pot = x @ W + b (+ boundary adds). No LDS staging: each thread
// streams one row-half (K=256) straight from global. K is split across the
// two waves of a pair (so W indices stay wave-uniform -> s_load broadcast);
// 8 float4 per chunk = exactly one 128B line per lane. Register double
// buffer; LDS only for the final half-sum reduction.
// Grid: 512 x 256 => 2048 waves = 2 waves/SIMD.
// ---------------------------------------------------------------------------
__global__ __launch_bounds__(256, 2) void gemm_pot(
    const float* __restrict__ x, const float* __restrict__ W,
    const float* __restrict__ bias, const float* __restrict__ trans,
    const float* __restrict__ lb, const float* __restrict__ rb,
    float* __restrict__ out)
{
  __shared__ float red[2][64][25];   // stride 25: coprime with 32 banks
  const int tid   = threadIdx.x;
  const int lane  = tid & 63;
  const int lw    = tid >> 6;        // local wave 0..3
  const int lp    = lw >> 1;         // local pair 0,1
  const int halfw = lw & 1;          // K-half handled by this wave
  const int gpair = blockIdx.x * 2 + lp;       // 0..1023
  const int row   = gpair * 64 + lane;         // 0..65535
  const float4* xr4 = (const float4*)(x + (size_t)row * DD + halfw * 256);

  float acc[NS];
#pragma unroll
  for (int nn = 0; nn < NS; ++nn) acc[nn] = 0.f;

  float4 buf[2][8];
#pragma unroll
  for (int i = 0; i < 8; ++i) buf[0][i] = xr4[i];

#pragma unroll
  for (int c = 0; c < 8; ++c) {
    const int cur = c & 1, nxt = cur ^ 1;
    if (c < 7) {
#pragma unroll
      for (int i = 0; i < 8; ++i) buf[nxt][i] = xr4[(c + 1) * 8 + i];
    }
    const int kb = halfw * 256 + c * 32;       // wave-uniform
#pragma unroll
    for (int i = 0; i < 8; ++i) {
      const float x0 = buf[cur][i].x, x1 = buf[cur][i].y;
      const float x2 = buf[cur][i].z, x3 = buf[cur][i].w;
      const float* Wr = W + (size_t)(kb + i * 4) * NS;   // wave-uniform -> s_load
#pragma unroll
      for (int nn = 0; nn < NS; ++nn) acc[nn] = fmaf(x0, Wr[nn], acc[nn]);
#pragma unroll
      for (int nn = 0; nn < NS; ++nn) acc[nn] = fmaf(x1, Wr[NS + nn], acc[nn]);
#pragma unroll
      for (int nn = 0; nn < NS; ++nn) acc[nn] = fmaf(x2, Wr[2 * NS + nn], acc[nn]);
#pragma unroll
      for (int nn = 0; nn < NS; ++nn) acc[nn] = fmaf(x3, Wr[3 * NS + nn], acc[nn]);
    }
  }

  if (halfw) {
#pragma unroll
    for (int nn = 0; nn < NS; ++nn) red[lp][lane][nn] = acc[nn];
  }
  __syncthreads();
  if (!halfw) {
    const int t = row & (TT - 1);
#pragma unroll
    for (int nn = 0; nn < NS; ++nn) acc[nn] = acc[nn] + red[lp][lane][nn] + bias[nn];
    if (t == 0) {
#pragma unroll
      for (int nn = 0; nn < NS; ++nn) acc[nn] += lb[nn];
    }
    if (t == TT - 1) {
#pragma unroll
      for (int nn = 0; nn < NS; ++nn) acc[nn] += rb[nn];
    }
    float* po = out + POT_OFF + (size_t)row * NS;
#pragma unroll
    for (int i = 0; i < 6; ++i)
      *(float4*)(po + i * 4) = make_float4(acc[4*i], acc[4*i+1], acc[4*i+2], acc[4*i+3]);
  }

  if (blockIdx.x == 0 && tid < BB) out[LENS_OFF + tid] = (float)TT;
  if (blockIdx.x == 1) {
    for (int i = tid; i < NS * NS; i += 256) out[TRANS_OFF + i] = trans[i];
  }
}

// ---------------------------------------------------------------------------
// Kernel 2 (fused): scan + bp + backtrace, one block per batch, 1024 threads.
// pot[b] staged to LDS; wave-0 scan writes alpha IN PLACE over consumed pot
// (ds_write, no vmcnt stall); bp built from LDS by all 16 waves; backtrace
// from LDS; decoded written straight to d_out. Alphas never touch global.
// ---------------------------------------------------------------------------
__global__ __launch_bounds__(1024) void viterbi_fused(
    const float* __restrict__ pot, const float* __restrict__ trans,
    float* __restrict__ out_dec)
{
  __shared__ float ps[(TT + 8) * NS];     // 99,072 B: pot, overwritten by alpha
  __shared__ unsigned char bl[TT * NS];   // 24,576 B: backpointers
  __shared__ float tl[NS * NS];           //  2,304 B: trans
  __shared__ int H[32][NS];
  __shared__ int e[32];

  const int b = blockIdx.x, tid = threadIdx.x;

  // ---- stage pot[b] + trans ----
  {
    const float4* src = (const float4*)(pot + (size_t)b * TT * NS);
    float4* dst = (float4*)ps;
#pragma unroll
    for (int i = 0; i < 6; ++i) dst[tid + i * 1024] = src[tid + i * 1024];
    if (tid < NS * NS) tl[tid] = trans[tid];
  }
  __syncthreads();

  // ---- forward scan: wave 0, lanes 0..23; alpha in SGPRs via readlane ----
  if (tid < 24) {
    const int n = tid;
    float tc[NS];
#pragma unroll
    for (int m = 0; m < NS; ++m) tc[m] = tl[m * NS + n];

    float a0 = ps[n];                    // ps row 0 already == alpha0
    float as[NS];
#pragma unroll
    for (int m = 0; m < NS; ++m)
      as[m] = __int_as_float(__builtin_amdgcn_readlane(__float_as_int(a0), m));

    float pv[8];
#pragma unroll
    for (int u = 0; u < 8; ++u) pv[u] = ps[(1 + u) * NS + n];

    auto step = [&](int tt, float potv) {
      float sc[NS];
#pragma unroll
      for (int m = 0; m < NS; ++m) sc[m] = as[m] + tc[m];
      float r0 = fmaxf(fmaxf(sc[0],  sc[1]),  sc[2]);
      float r1 = fmaxf(fmaxf(sc[3],  sc[4]),  sc[5]);
      float r2 = fmaxf(fmaxf(sc[6],  sc[7]),  sc[8]);
      float r3 = fmaxf(fmaxf(sc[9],  sc[10]), sc[11]);
      float r4 = fmaxf(fmaxf(sc[12], sc[13]), sc[14]);
      float r5 = fmaxf(fmaxf(sc[15], sc[16]), sc[17]);
      float r6 = fmaxf(fmaxf(sc[18], sc[19]), sc[20]);
      float r7 = fmaxf(fmaxf(sc[21], sc[22]), sc[23]);
      float q0 = fmaxf(fmaxf(r0, r1), r2);
      float q1 = fmaxf(fmaxf(r3, r4), r5);
      float q2 = fmaxf(r6, r7);
      float best = fmaxf(fmaxf(q0, q1), q2);
      float anew = best + potv;
      ps[tt * NS + n] = anew;            // in-place: slot tt already consumed
#pragma unroll
      for (int m = 0; m < NS; ++m)
        as[m] = __int_as_float(__builtin_amdgcn_readlane(__float_as_int(anew), m));
    };

    for (int t = 1; t + 7 <= TT - 1; t += 8) {
#pragma unroll
      for (int u = 0; u < 8; ++u) {
        const int tt = t + u;
        const float potv = pv[u];
        pv[u] = ps[(tt + 8) * NS + n];   // read 8 ahead of any write
        step(tt, potv);
      }
    }
#pragma unroll
    for (int u = 0; u < 7; ++u) step(1017 + u, pv[u]);
  }
  __syncthreads();

  // ---- bp build from LDS alphas (bit-exact, first-max strict >) ----
  for (int idx = tid; idx < (TT - 1) * NS; idx += 1024) {
    const int n = idx % NS;
    const int t = idx / NS + 1;
    const float* ar = &ps[(t - 1) * NS];   // 24-lane groups share row: broadcast
    float best = ar[0] + tl[n];
    int bi = 0;
#pragma unroll
    for (int m = 1; m < NS; ++m) {
      float s = ar[m] + tl[m * NS + n];
      bool g = s > best;
      bi = g ? m : bi;
      best = g ? s : best;
    }
    bl[t * NS + n] = (unsigned char)bi;
  }
  __syncthreads();

  // ---- backtrace: chunk composition (C=32) ----
  if (tid < 32 * NS) {
    const int c = tid / NS, s = tid % NS;
    int a = s;
    int tlo = c * 32; if (tlo < 1) tlo = 1;
    for (int t = c * 32 + 31; t >= tlo; --t) a = bl[t * NS + a];
    H[c][s] = a;
  }
  __syncthreads();

  if (tid == 0) {
    const float* ar = &ps[(TT - 1) * NS];
    float best = ar[0]; int bi = 0;
#pragma unroll
    for (int nn = 1; nn < NS; ++nn) {
      float v = ar[nn];
      if (v > best) { best = v; bi = nn; }
    }
    int tag = bi;
    e[31] = tag;
    for (int c = 31; c >= 1; --c) { tag = H[c][tag]; e[c - 1] = tag; }
  }
  __syncthreads();

  if (tid < 32) {
    const int c = tid;
    int tag = e[c];
    float* od = out_dec + (size_t)b * TT;
    od[c * 32 + 31] = (float)tag;
    for (int t = c * 32 + 30; t >= c * 32; --t) {
      tag = bl[(t + 1) * NS + tag];
      od[t] = (float)tag;
    }
  }
}

// ---------------------------------------------------------------------------
extern "C" void kernel_launch(void* const* d_in, const int* in_sizes, int n_in,
                              void* d_out, int out_size, void* d_ws, size_t ws_size,
                              hipStream_t stream)
{
  const float* x     = (const float*)d_in[0];
  const float* W     = (const float*)d_in[1];
  const float* bias  = (const float*)d_in[2];
  const float* trans = (const float*)d_in[3];
  const float* lb    = (const float*)d_in[4];
  const float* rb    = (const float*)d_in[5];
  float* out = (float*)d_out;

  gemm_pot<<<512, 256, 0, stream>>>(x, W, bias, trans, lb, rb, out);
  viterbi_fused<<<BB, 1024, 0, stream>>>(out + POT_OFF, trans, out);
}

// Round 4
// 432.397 us; speedup vs baseline: 1.2127x; 1.0932x over previous
//
#include <hip/hip_runtime.h>
#include <hip/hip_bf16.h>

#define BB 64
#define TT 1024
#define DD 512
#define NS 24

#define POT_OFF   65536
#define LENS_OFF  1638400
#define TRANS_OFF 1638464

// ---------------------------------------------------------------------------
// Kernel 1: pot = x @ W + b (+ boundary adds). TLP design: 1024 blocks x 256
// threads = 4096 waves (4/SIMD). Thread (lane l, wave q) owns K-quarter q of
// row blockIdx*64+l: 8 chunks of {4 float4 loads, 384 FMAs}. Loads precede
// uses in program order (no prefetch liveness for the compiler to kill);
// 4 waves/SIMD hide HBM latency. W indices wave-uniform -> s_load broadcast.
// Quarter partials reduced through LDS.
// ---------------------------------------------------------------------------
__global__ __launch_bounds__(256, 4) void gemm_pot(
    const float* __restrict__ x, const float* __restrict__ W,
    const float* __restrict__ bias, const float* __restrict__ trans,
    const float* __restrict__ lb, const float* __restrict__ rb,
    float* __restrict__ out)
{
  __shared__ float red[3][64][25];     // stride 25: coprime with 32 banks
  const int tid  = threadIdx.x;
  const int l    = tid & 63;           // lane -> row within block
  const int q    = tid >> 6;           // wave -> K quarter
  const int row  = blockIdx.x * 64 + l;

  const float4* xp = (const float4*)(x + (size_t)row * DD + q * 128);

  float acc[NS];
#pragma unroll
  for (int nn = 0; nn < NS; ++nn) acc[nn] = 0.f;

#pragma unroll
  for (int c = 0; c < 8; ++c) {
    float4 t0 = xp[c * 4 + 0];
    float4 t1 = xp[c * 4 + 1];
    float4 t2 = xp[c * 4 + 2];
    float4 t3 = xp[c * 4 + 3];
    const int kb = q * 128 + c * 16;               // wave-uniform
    const float* Wr = W + (size_t)kb * NS;         // -> s_load rows
    const float xs[16] = {t0.x,t0.y,t0.z,t0.w, t1.x,t1.y,t1.z,t1.w,
                          t2.x,t2.y,t2.z,t2.w, t3.x,t3.y,t3.z,t3.w};
#pragma unroll
    for (int j = 0; j < 16; ++j) {
      const float xv = xs[j];
#pragma unroll
      for (int nn = 0; nn < NS; ++nn)
        acc[nn] = fmaf(xv, Wr[j * NS + nn], acc[nn]);
    }
  }

  if (q != 0) {
#pragma unroll
    for (int nn = 0; nn < NS; ++nn) red[q - 1][l][nn] = acc[nn];
  }
  __syncthreads();
  if (q == 0) {
    const int t = row & (TT - 1);
#pragma unroll
    for (int nn = 0; nn < NS; ++nn)
      acc[nn] += red[0][l][nn] + red[1][l][nn] + red[2][l][nn] + bias[nn];
    if (t == 0) {
#pragma unroll
      for (int nn = 0; nn < NS; ++nn) acc[nn] += lb[nn];
    }
    if (t == TT - 1) {
#pragma unroll
      for (int nn = 0; nn < NS; ++nn) acc[nn] += rb[nn];
    }
    float* po = out + POT_OFF + (size_t)row * NS;
#pragma unroll
    for (int i = 0; i < 6; ++i)
      *(float4*)(po + i * 4) = make_float4(acc[4*i], acc[4*i+1], acc[4*i+2], acc[4*i+3]);
  }

  if (blockIdx.x == 0 && tid < BB) out[LENS_OFF + tid] = (float)TT;
  if (blockIdx.x == 1) {
    for (int i = tid; i < NS * NS; i += 256) out[TRANS_OFF + i] = trans[i];
  }
}

// ---------------------------------------------------------------------------
// Kernel 2 (fused): scan + bp + backtrace, one block per batch, 1024 threads.
// Scan: wave 0, lanes 0..23. Alpha broadcast via 6 same-address ds_read_b128
// (NOT readlane -> no cross-lane/SGPR-hazard cost). Alpha overwrites pot in
// place in LDS; DS in-order within a wave => no barrier in the scan loop.
// ---------------------------------------------------------------------------
__global__ __launch_bounds__(1024) void viterbi_fused(
    const float* __restrict__ pot, const float* __restrict__ trans,
    float* __restrict__ out_dec)
{
  __shared__ float ps[(TT + 8) * NS];     // 99,072 B: pot, overwritten by alpha
  __shared__ unsigned char bl[TT * NS];   // 24,576 B: backpointers
  __shared__ float tl[NS * NS];           //  2,304 B: trans
  __shared__ int H[32][NS];
  __shared__ int e[32];

  const int b = blockIdx.x, tid = threadIdx.x;

  // ---- stage pot[b] + trans ----
  {
    const float4* src = (const float4*)(pot + (size_t)b * TT * NS);
    float4* dst = (float4*)ps;
#pragma unroll
    for (int i = 0; i < 6; ++i) dst[tid + i * 1024] = src[tid + i * 1024];
    if (tid < NS * NS) tl[tid] = trans[tid];
  }
  __syncthreads();

  // ---- forward scan ----
  if (tid < 24) {
    const int n = tid;
    float tc[NS];
#pragma unroll
    for (int m = 0; m < NS; ++m) tc[m] = tl[m * NS + n];

    float as_[NS];                       // alpha row, replicated in all lanes
    {
      const float4* ar = (const float4*)ps;   // row 0 == alpha0
#pragma unroll
      for (int i = 0; i < 6; ++i) {
        float4 v = ar[i];
        as_[4*i] = v.x; as_[4*i+1] = v.y; as_[4*i+2] = v.z; as_[4*i+3] = v.w;
      }
    }

    float pv[8];
#pragma unroll
    for (int u = 0; u < 8; ++u) pv[u] = ps[(1 + u) * NS + n];

    auto step = [&](int tt, float potv) {
      float sc[NS];
#pragma unroll
      for (int m = 0; m < NS; ++m) sc[m] = as_[m] + tc[m];
      float r0 = fmaxf(fmaxf(sc[0],  sc[1]),  sc[2]);
      float r1 = fmaxf(fmaxf(sc[3],  sc[4]),  sc[5]);
      float r2 = fmaxf(fmaxf(sc[6],  sc[7]),  sc[8]);
      float r3 = fmaxf(fmaxf(sc[9],  sc[10]), sc[11]);
      float r4 = fmaxf(fmaxf(sc[12], sc[13]), sc[14]);
      float r5 = fmaxf(fmaxf(sc[15], sc[16]), sc[17]);
      float r6 = fmaxf(fmaxf(sc[18], sc[19]), sc[20]);
      float r7 = fmaxf(fmaxf(sc[21], sc[22]), sc[23]);
      float q0 = fmaxf(fmaxf(r0, r1), r2);
      float q1 = fmaxf(fmaxf(r3, r4), r5);
      float q2 = fmaxf(r6, r7);
      float best = fmaxf(fmaxf(q0, q1), q2);
      float anew = best + potv;
      ps[tt * NS + n] = anew;            // 24 lanes write the row...
      const float4* ar = (const float4*)(ps + tt * NS);
#pragma unroll
      for (int i = 0; i < 6; ++i) {      // ...then all lanes broadcast-read it
        float4 v = ar[i];                // (same wave: DS in-order, no barrier)
        as_[4*i] = v.x; as_[4*i+1] = v.y; as_[4*i+2] = v.z; as_[4*i+3] = v.w;
      }
    };

    for (int t = 1; t + 7 <= TT - 1; t += 8) {
#pragma unroll
      for (int u = 0; u < 8; ++u) {
        const int tt = t + u;
        const float potv = pv[u];
        pv[u] = ps[(tt + 8) * NS + n];   // 8 ahead of the overwrite frontier
        step(tt, potv);
      }
    }
#pragma unroll
    for (int u = 0; u < 7; ++u) step(1017 + u, pv[u]);
  }
  __syncthreads();

  // ---- bp build from LDS alphas (bit-exact, first-max strict >) ----
  for (int idx = tid; idx < (TT - 1) * NS; idx += 1024) {
    const int n = idx % NS;
    const int t = idx / NS + 1;
    const float* ar = &ps[(t - 1) * NS];
    float best = ar[0] + tl[n];
    int bi = 0;
#pragma unroll
    for (int m = 1; m < NS; ++m) {
      float s = ar[m] + tl[m * NS + n];
      bool g = s > best;
      bi = g ? m : bi;
      best = g ? s : best;
    }
    bl[t * NS + n] = (unsigned char)bi;
  }
  __syncthreads();

  // ---- backtrace: chunk composition (C=32) ----
  if (tid < 32 * NS) {
    const int c = tid / NS, s = tid % NS;
    int a = s;
    int tlo = c * 32; if (tlo < 1) tlo = 1;
    for (int t = c * 32 + 31; t >= tlo; --t) a = bl[t * NS + a];
    H[c][s] = a;
  }
  __syncthreads();

  if (tid == 0) {
    const float* ar = &ps[(TT - 1) * NS];
    float best = ar[0]; int bi = 0;
#pragma unroll
    for (int nn = 1; nn < NS; ++nn) {
      float v = ar[nn];
      if (v > best) { best = v; bi = nn; }
    }
    int tag = bi;
    e[31] = tag;
    for (int c = 31; c >= 1; --c) { tag = H[c][tag]; e[c - 1] = tag; }
  }
  __syncthreads();

  if (tid < 32) {
    const int c = tid;
    int tag = e[c];
    float* od = out_dec + (size_t)b * TT;
    od[c * 32 + 31] = (float)tag;
    for (int t = c * 32 + 30; t >= c * 32; --t) {
      tag = bl[(t + 1) * NS + tag];
      od[t] = (float)tag;
    }
  }
}

// ---------------------------------------------------------------------------
extern "C" void kernel_launch(void* const* d_in, const int* in_sizes, int n_in,
                              void* d_out, int out_size, void* d_ws, size_t ws_size,
                              hipStream_t stream)
{
  const float* x     = (const float*)d_in[0];
  const float* W     = (const float*)d_in[1];
  const float* bias  = (const float*)d_in[2];
  const float* trans = (const float*)d_in[3];
  const float* lb    = (const float*)d_in[4];
  const float* rb    = (const float*)d_in[5];
  float* out = (float*)d_out;

  gemm_pot<<<1024, 256, 0, stream>>>(x, W, bias, trans, lb, rb, out);
  viterbi_fused<<<BB, 1024, 0, stream>>>(out + POT_OFF, trans, out);
}

// Round 5
// 382.232 us; speedup vs baseline: 1.3718x; 1.1312x over previous
//
#include <hip/hip_runtime.h>
#include <hip/hip_bf16.h>

#define BB 64
#define TT 1024
#define DD 512
#define NS 24

#define POT_OFF   65536
#define LENS_OFF  1638400
#define TRANS_OFF 1638464

// ---------------------------------------------------------------------------
// Kernel 1: pot = x @ W + b (+ boundary adds). 1024 blocks x 256 threads =
// 4 waves/SIMD. Thread (lane l, wave q) owns K-quarter q of row blk*64+l.
// q is forced into an SGPR via readfirstlane so ALL W addressing is provably
// scalar -> s_load broadcast + v_fmac(s,v): 1 VALU instr per MAC.
// ---------------------------------------------------------------------------
__global__ __launch_bounds__(256, 4) void gemm_pot(
    const float* __restrict__ x, const float* __restrict__ W,
    const float* __restrict__ bias, const float* __restrict__ trans,
    const float* __restrict__ lb, const float* __restrict__ rb,
    float* __restrict__ out)
{
  __shared__ float red[3][64][25];     // stride 25: coprime with 32 banks
  const int tid = threadIdx.x;
  const int l   = tid & 63;
  const int q   = __builtin_amdgcn_readfirstlane(tid >> 6);   // wave-uniform SGPR
  const int row = blockIdx.x * 64 + l;

  const float4* xp = (const float4*)(x + (size_t)row * DD + q * 128);

  float acc[NS];
#pragma unroll
  for (int nn = 0; nn < NS; ++nn) acc[nn] = 0.f;

#pragma unroll
  for (int c = 0; c < 8; ++c) {
    float4 t0 = xp[c * 4 + 0];
    float4 t1 = xp[c * 4 + 1];
    float4 t2 = xp[c * 4 + 2];
    float4 t3 = xp[c * 4 + 3];
    const float* Wr = W + (size_t)(q * 128 + c * 16) * NS;    // scalar address
    const float xs[16] = {t0.x,t0.y,t0.z,t0.w, t1.x,t1.y,t1.z,t1.w,
                          t2.x,t2.y,t2.z,t2.w, t3.x,t3.y,t3.z,t3.w};
#pragma unroll
    for (int j = 0; j < 16; ++j) {
      const float xv = xs[j];
#pragma unroll
      for (int nn = 0; nn < NS; ++nn)
        acc[nn] = fmaf(xv, Wr[j * NS + nn], acc[nn]);         // s_load W operand
    }
  }

  if (q != 0) {
#pragma unroll
    for (int nn = 0; nn < NS; ++nn) red[q - 1][l][nn] = acc[nn];
  }
  __syncthreads();
  if (q == 0) {
    const int t = row & (TT - 1);
#pragma unroll
    for (int nn = 0; nn < NS; ++nn)
      acc[nn] += red[0][l][nn] + red[1][l][nn] + red[2][l][nn] + bias[nn];
    if (t == 0) {
#pragma unroll
      for (int nn = 0; nn < NS; ++nn) acc[nn] += lb[nn];
    }
    if (t == TT - 1) {
#pragma unroll
      for (int nn = 0; nn < NS; ++nn) acc[nn] += rb[nn];
    }
    float* po = out + POT_OFF + (size_t)row * NS;
#pragma unroll
    for (int i = 0; i < 6; ++i)
      *(float4*)(po + i * 4) = make_float4(acc[4*i], acc[4*i+1], acc[4*i+2], acc[4*i+3]);
  }

  if (blockIdx.x == 0 && tid < BB) out[LENS_OFF + tid] = (float)TT;
  if (blockIdx.x == 1) {
    for (int i = tid; i < NS * NS; i += 256) out[TRANS_OFF + i] = trans[i];
  }
}

// ---------------------------------------------------------------------------
// Kernel 2 (fused): scan + bp + backtrace, one block per batch.
// Scan: wave 0, lanes (g = l>>5, n = l&31). Alpha broadcast via ds_bpermute
// (register space, ~35 cyc latency, no LDS round-trip). m-reduction split
// over the two g groups (12 adds each), combined with one partner bpermute.
// Alphas stored to LDS (off critical path) for the bp/backtrace phases.
// ---------------------------------------------------------------------------
__global__ __launch_bounds__(1024) void viterbi_fused(
    const float* __restrict__ pot, const float* __restrict__ trans,
    float* __restrict__ out_dec)
{
  __shared__ float ps[(TT + 8) * NS + 64];  // pot rows, overwritten by alpha; +dump row
  __shared__ unsigned char bl[TT * NS];     // backpointers
  __shared__ float tl[NS * NS];             // trans
  __shared__ int H[32][NS];
  __shared__ int e[32];

  const int b = blockIdx.x, tid = threadIdx.x;
  const int DUMP = (TT + 8) * NS;           // scratch row for invalid-lane stores

  // ---- stage pot[b] + trans ----
  {
    const float4* src = (const float4*)(pot + (size_t)b * TT * NS);
    float4* dst = (float4*)ps;
#pragma unroll
    for (int i = 0; i < 6; ++i) dst[tid + i * 1024] = src[tid + i * 1024];
    if (tid < NS * NS) tl[tid] = trans[tid];
  }
  __syncthreads();

  // ---- forward scan: wave 0 ----
  if (tid < 64) {
    const int l = tid;
    const int g = l >> 5;                   // m-group 0/1
    const int n = l & 31;                   // state (valid when n<24)
    const bool valid = (g == 0) && (n < 24);
    const int nc = (n < 24) ? n : 23;       // clamp for junk lanes

    float tc[12];
    int srcidx[12];
#pragma unroll
    for (int j = 0; j < 12; ++j) {
      const int m = 12 * g + j;
      tc[j] = tl[m * NS + nc];
      srcidx[j] = 4 * m;                    // alpha[m] lives in lane m
    }
    const int partner = 4 * (((g ^ 1) << 5) + n);

    float anew = ps[l];                     // lanes 0..23 hold alpha0[l]

    float pv[8];
#pragma unroll
    for (int u = 0; u < 8; ++u) pv[u] = ps[(1 + u) * NS + nc];

    auto step = [&](int tt, float potv) {
      float as[12];
#pragma unroll
      for (int j = 0; j < 12; ++j)
        as[j] = __int_as_float(
            __builtin_amdgcn_ds_bpermute(srcidx[j], __float_as_int(anew)));
      float sc[12];
#pragma unroll
      for (int j = 0; j < 12; ++j) sc[j] = as[j] + tc[j];
      float r0 = fmaxf(fmaxf(sc[0], sc[1]),  sc[2]);
      float r1 = fmaxf(fmaxf(sc[3], sc[4]),  sc[5]);
      float r2 = fmaxf(fmaxf(sc[6], sc[7]),  sc[8]);
      float r3 = fmaxf(fmaxf(sc[9], sc[10]), sc[11]);
      float pmax = fmaxf(fmaxf(r0, r1), fmaxf(r2, r3));
      float other = __int_as_float(
          __builtin_amdgcn_ds_bpermute(partner, __float_as_int(pmax)));
      float best = fmaxf(pmax, other);
      anew = best + potv;                   // single add: matches ref rounding
      const int addr = valid ? (tt * NS + n) : (DUMP + l);
      ps[addr] = anew;                      // off-chain store for bp phase
    };

    for (int t = 1; t + 7 <= TT - 1; t += 8) {
#pragma unroll
      for (int u = 0; u < 8; ++u) {
        const int tt = t + u;
        const float potv = pv[u];
        pv[u] = ps[(tt + 8) * NS + nc];     // 8 ahead of overwrite frontier
        step(tt, potv);
      }
    }
#pragma unroll
    for (int u = 0; u < 7; ++u) step(1017 + u, pv[u]);
  }
  __syncthreads();

  // ---- bp build from LDS alphas (bit-exact, first-max strict >) ----
  for (int idx = tid; idx < (TT - 1) * NS; idx += 1024) {
    const int n = idx % NS;
    const int t = idx / NS + 1;
    const float* ar = &ps[(t - 1) * NS];
    float best = ar[0] + tl[n];
    int bi = 0;
#pragma unroll
    for (int m = 1; m < NS; ++m) {
      float s = ar[m] + tl[m * NS + n];
      bool gg = s > best;
      bi = gg ? m : bi;
      best = gg ? s : best;
    }
    bl[t * NS + n] = (unsigned char)bi;
  }
  __syncthreads();

  // ---- backtrace: chunk composition (C=32) ----
  if (tid < 32 * NS) {
    const int c = tid / NS, s = tid % NS;
    int a = s;
    int tlo = c * 32; if (tlo < 1) tlo = 1;
    for (int t = c * 32 + 31; t >= tlo; --t) a = bl[t * NS + a];
    H[c][s] = a;
  }
  __syncthreads();

  if (tid == 0) {
    const float* ar = &ps[(TT - 1) * NS];
    float best = ar[0]; int bi = 0;
#pragma unroll
    for (int nn = 1; nn < NS; ++nn) {
      float v = ar[nn];
      if (v > best) { best = v; bi = nn; }
    }
    int tag = bi;
    e[31] = tag;
    for (int c = 31; c >= 1; --c) { tag = H[c][tag]; e[c - 1] = tag; }
  }
  __syncthreads();

  if (tid < 32) {
    const int c = tid;
    int tag = e[c];
    float* od = out_dec + (size_t)b * TT;
    od[c * 32 + 31] = (float)tag;
    for (int t = c * 32 + 30; t >= c * 32; --t) {
      tag = bl[(t + 1) * NS + tag];
      od[t] = (float)tag;
    }
  }
}

// ---------------------------------------------------------------------------
extern "C" void kernel_launch(void* const* d_in, const int* in_sizes, int n_in,
                              void* d_out, int out_size, void* d_ws, size_t ws_size,
                              hipStream_t stream)
{
  const float* x     = (const float*)d_in[0];
  const float* W     = (const float*)d_in[1];
  const float* bias  = (const float*)d_in[2];
  const float* trans = (const float*)d_in[3];
  const float* lb    = (const float*)d_in[4];
  const float* rb    = (const float*)d_in[5];
  float* out = (float*)d_out;

  gemm_pot<<<1024, 256, 0, stream>>>(x, W, bias, trans, lb, rb, out);
  viterbi_fused<<<BB, 1024, 0, stream>>>(out + POT_OFF, trans, out);
}